// Round 3
// baseline (395.104 us; speedup 1.0000x reference)
//
#include <hip/hip_runtime.h>

// r = 1 - cov(x,y)/sqrt(|var(x)*var(y)|) per row (cov identity), mean over 768.
// Pass 1: 5 sufficient stats per (row,chunk) block. Pass 2: combine -> mean.
//
// R5: three codegens (VGPR 32/36/72, occ 24-61%) all pinned at 2.9-3.4 TB/s
// delivered read BW while write-only fill hits 6.8 TB/s => the cap is in the
// VGPR load-return path, not HBM. This version reads through the DMA path:
// __builtin_amdgcn_global_load_lds (no VGPR destinations), 8 tiles of
// 512 f4 (x) + 512 f4 (y) per block, 4-slot LDS ring, 3 tiles in flight,
// counted s_waitcnt vmcnt(12/8/4/0) + raw s_barrier (NOT __syncthreads,
// which drains vmcnt(0) and would serialize the pipeline).
// Per-thread accumulation order is bit-exact with the previous kernel.

#define ROWS 768          // 8*16*6
#define ROW_ELEMS 65536   // 256*256
#define BLOCK 256
#define SPLIT 4                         // chunks per row
#define NBLK (ROWS * SPLIT)             // 3072 partial blocks
#define CHUNK_F4 4096                   // f4 per tensor per block
#define TILE_F4 512                     // f4 per tensor per tile (8 tiles)

typedef float f4 __attribute__((ext_vector_type(4)));

__global__ __launch_bounds__(BLOCK) void partial_kernel(const float* __restrict__ x,
                                                        const float* __restrict__ y,
                                                        float* __restrict__ part) {
    const int blk = blockIdx.x;          // row*SPLIT + chunk
    const size_t base = (size_t)blk * (ROW_ELEMS / SPLIT);
    const f4* __restrict__ x4 = (const f4*)(x + base);
    const f4* __restrict__ y4 = (const f4*)(y + base);
    const int tid = threadIdx.x;
    const int w = tid >> 6;              // wave id (uniform per wave)
    const int l = tid & 63;              // lane

    // 4 ring slots x (512 x-f4 + 512 y-f4) = 64 KB
    __shared__ f4 ldsx[4][TILE_F4];
    __shared__ f4 ldsy[4][TILE_F4];

    f4 vsx = {0.f, 0.f, 0.f, 0.f};
    f4 vsy = {0.f, 0.f, 0.f, 0.f};
    f4 vsxx = {0.f, 0.f, 0.f, 0.f};
    f4 vsyy = {0.f, 0.f, 0.f, 0.f};
    f4 vsxy = {0.f, 0.f, 0.f, 0.f};

    // Stage tile t into ring slot s. Per wave: 2 q-groups x (1 x + 1 y) = 4
    // DMA ops of 1 KB each (64 lanes x 16 B). LDS dest is wave-uniform;
    // HW adds lane*16. Layout is linear => consume indices match source.
    #define STAGE(t, s)                                                          \
    {                                                                            \
        _Pragma("unroll")                                                        \
        for (int q = 0; q < 2; ++q) {                                            \
            const f4* sxp = x4 + (t) * TILE_F4 + q * 256 + w * 64 + l;           \
            const f4* syp = y4 + (t) * TILE_F4 + q * 256 + w * 64 + l;           \
            __builtin_amdgcn_global_load_lds(                                    \
                (const __attribute__((address_space(1))) unsigned int*)sxp,      \
                (__attribute__((address_space(3))) unsigned int*)&ldsx[s][q * 256 + w * 64], \
                16, 0, 0);                                                       \
            __builtin_amdgcn_global_load_lds(                                    \
                (const __attribute__((address_space(1))) unsigned int*)syp,      \
                (__attribute__((address_space(3))) unsigned int*)&ldsy[s][q * 256 + w * 64], \
                16, 0, 0);                                                       \
        }                                                                        \
    }

    // Consume tile t from slot s: thread tid takes f4 indices tid, tid+256
    // (global j = t*2 + jj, ascending) -- bit-identical order to R0-R2.
    #define CONSUME(t, s)                                                        \
    {                                                                            \
        _Pragma("unroll")                                                        \
        for (int jj = 0; jj < 2; ++jj) {                                         \
            f4 a = ldsx[s][tid + jj * 256];                                      \
            f4 b = ldsy[s][tid + jj * 256];                                      \
            vsx += a; vsy += b;                                                  \
            vsxx += a * a; vsyy += b * b; vsxy += a * b;                         \
        }                                                                        \
    }

    // One pipeline step: optional stage of tile (t+3), wait for tile t's 4
    // DMA ops (vm = 4 * tiles-still-outstanding-after-t), barrier so ALL
    // waves' stages for t are visible, consume, then barrier so the slot
    // can be overwritten next iteration.
    #define STEP(t, vm, STAGE_STMT)                                              \
    {                                                                            \
        STAGE_STMT;                                                              \
        asm volatile("s_waitcnt vmcnt(" #vm ")" ::: "memory");                   \
        __builtin_amdgcn_s_barrier();                                            \
        __builtin_amdgcn_sched_barrier(0);                                       \
        CONSUME(t, (t) & 3);                                                     \
        asm volatile("s_waitcnt lgkmcnt(0)" ::: "memory");                       \
        __builtin_amdgcn_sched_barrier(0);                                       \
        __builtin_amdgcn_s_barrier();                                            \
    }

    // Prologue: 3 tiles ahead.
    STAGE(0, 0);
    STAGE(1, 1);
    STAGE(2, 2);

    STEP(0, 12, STAGE(3, 3));
    STEP(1, 12, STAGE(4, 0));
    STEP(2, 12, STAGE(5, 1));
    STEP(3, 12, STAGE(6, 2));
    STEP(4, 12, STAGE(7, 3));
    STEP(5, 8, );
    STEP(6, 4, );
    STEP(7, 0, );

    #undef STEP
    #undef CONSUME
    #undef STAGE

    // horizontal reduce vector accumulators to scalars
    float sx  = vsx.x  + vsx.y  + vsx.z  + vsx.w;
    float sy  = vsy.x  + vsy.y  + vsy.z  + vsy.w;
    float sxx = vsxx.x + vsxx.y + vsxx.z + vsxx.w;
    float syy = vsyy.x + vsyy.y + vsyy.z + vsyy.w;
    float sxy = vsxy.x + vsxy.y + vsxy.z + vsxy.w;

    // 64-lane wave shuffle reduction
    #pragma unroll
    for (int off = 32; off > 0; off >>= 1) {
        sx  += __shfl_down(sx,  off);
        sy  += __shfl_down(sy,  off);
        sxx += __shfl_down(sxx, off);
        syy += __shfl_down(syy, off);
        sxy += __shfl_down(sxy, off);
    }

    __shared__ float sm[5][BLOCK / 64];
    if (l == 0) {
        sm[0][w] = sx;  sm[1][w] = sy;
        sm[2][w] = sxx; sm[3][w] = syy;
        sm[4][w] = sxy;
    }
    __syncthreads();

    if (tid == 0) {
        float t0 = 0.f, t1 = 0.f, t2 = 0.f, t3 = 0.f, t4 = 0.f;
        #pragma unroll
        for (int ww = 0; ww < BLOCK / 64; ++ww) {
            t0 += sm[0][ww]; t1 += sm[1][ww];
            t2 += sm[2][ww]; t3 += sm[3][ww];
            t4 += sm[4][ww];
        }
        // struct-of-arrays for coalesced reads in pass 2
        part[0 * NBLK + blk] = t0;
        part[1 * NBLK + blk] = t1;
        part[2 * NBLK + blk] = t2;
        part[3 * NBLK + blk] = t3;
        part[4 * NBLK + blk] = t4;
    }
}

__global__ __launch_bounds__(BLOCK) void finalize_kernel(const float* __restrict__ part,
                                                         float* __restrict__ out) {
    float acc = 0.f;
    for (int row = threadIdx.x; row < ROWS; row += BLOCK) {
        float tsx = 0.f, tsy = 0.f, tsxx = 0.f, tsyy = 0.f, tsxy = 0.f;
        #pragma unroll
        for (int c = 0; c < SPLIT; ++c) {
            const int b = row * SPLIT + c;
            tsx  += part[0 * NBLK + b];
            tsy  += part[1 * NBLK + b];
            tsxx += part[2 * NBLK + b];
            tsyy += part[3 * NBLK + b];
            tsxy += part[4 * NBLK + b];
        }
        const float n = (float)ROW_ELEMS;
        const float inv_nm1 = 1.0f / (n - 1.0f);
        float vx  = (tsxx - tsx * tsx / n) * inv_nm1;
        float vy  = (tsyy - tsy * tsy / n) * inv_nm1;
        float cov = (tsxy - tsx * tsy / n) * inv_nm1;
        acc += 1.0f - cov / sqrtf(fabsf(vx * vy));
    }

    #pragma unroll
    for (int off = 32; off > 0; off >>= 1) acc += __shfl_down(acc, off);

    __shared__ float sm[BLOCK / 64];
    const int wave = threadIdx.x >> 6;
    const int lane = threadIdx.x & 63;
    if (lane == 0) sm[wave] = acc;
    __syncthreads();

    if (threadIdx.x == 0) {
        float t = 0.f;
        #pragma unroll
        for (int w = 0; w < BLOCK / 64; ++w) t += sm[w];
        out[0] = t / (float)ROWS;
    }
}

extern "C" void kernel_launch(void* const* d_in, const int* in_sizes, int n_in,
                              void* d_out, int out_size, void* d_ws, size_t ws_size,
                              hipStream_t stream) {
    const float* x = (const float*)d_in[0];
    const float* y = (const float*)d_in[1];
    float* part = (float*)d_ws;   // 5 * 3072 floats = 60 KB scratch
    float* out = (float*)d_out;

    partial_kernel<<<NBLK, BLOCK, 0, stream>>>(x, y, part);
    finalize_kernel<<<1, BLOCK, 0, stream>>>(part, out);
}